// Round 1
// baseline (17259.886 us; speedup 1.0000x reference)
//
#include <hip/hip_runtime.h>
#include <cstdint>

#define SEQ   2048
#define BATCH 128
#define IN    64
#define HID   256
#define OUTD  64
#define G4    1024

#define T     512
#define NHH   32   // W_hh 8-dim chunks (256 dims), all register-resident
#define NIH   8    // W_ih 8-dim chunks (64 inputs), all register-resident

// ws layout in dwords (single copies — loads are hoisted out of the loop now)
#define OFF_WHH 0
#define SZ_WHH  (2*NHH*512*4)          // 131072 dw = 512 KiB
#define OFF_WIH (OFF_WHH+SZ_WHH)       // 131072
#define SZ_WIH  (2*NIH*512*4)          // 32768 dw = 128 KiB
#define OFF_WOUT (OFF_WIH+SZ_WIH)      // 163840
#define SZ_WOUT 8192                   // 64*256 f16 = 32 KiB
#define TOTAL_DW (OFF_WOUT+SZ_WOUT)    // 172032 dw = 672 KiB of ws

typedef _Float16 f16x2 __attribute__((ext_vector_type(2)));

__device__ __forceinline__ float fexp2(float v) { return __builtin_amdgcn_exp2f(v); }
__device__ __forceinline__ float frcp(float v)  { return __builtin_amdgcn_rcpf(v); }
__device__ __forceinline__ float fsig(float v)  { return frcp(1.0f + fexp2(v * -1.44269504088896f)); }
__device__ __forceinline__ float ftanh_(float v){ return 1.0f - 2.0f * frcp(1.0f + fexp2(v * 2.88539008177793f)); }

__device__ __forceinline__ unsigned int pack2d(float a, float b) {
  unsigned short lo = __builtin_bit_cast(unsigned short, (_Float16)a);
  unsigned short hi = __builtin_bit_cast(unsigned short, (_Float16)b);
  return (unsigned int)lo | ((unsigned int)hi << 16);
}

__device__ __forceinline__ float dot2f(unsigned int w, unsigned int h, float acc) {
#if __has_builtin(__builtin_amdgcn_fdot2)
  return __builtin_amdgcn_fdot2(__builtin_bit_cast(f16x2, w), __builtin_bit_cast(f16x2, h), acc, false);
#else
  f16x2 a = __builtin_bit_cast(f16x2, w), b = __builtin_bit_cast(f16x2, h);
  return acc + (float)a.x * (float)b.x + (float)a.y * (float)b.y;
#endif
}

__device__ __forceinline__ void mac8(uint4 w, uint4 h, float& acc) {
  acc = dot2f(w.x, h.x, acc);
  acc = dot2f(w.y, h.y, acc);
  acc = dot2f(w.z, h.z, acc);
  acc = dot2f(w.w, h.w, acc);
}

// ---------------- prep: fp32 weights -> packed f16 layouts in ws ----------------
__global__ void prep_weights(const float* __restrict__ Whh, const float* __restrict__ Wih,
                             const float* __restrict__ Wout, unsigned int* __restrict__ ws) {
  int tid = blockIdx.x * 256 + threadIdx.x;
  if (tid >= TOTAL_DW) return;
  unsigned int val;
  if (tid < OFF_WIH) {                                   // W_hh: rest = r*32+j
    int q = tid & 3, t = (tid >> 2) & 511, rest = tid >> 11;
    int j = rest & 31, r2 = rest >> 5;
    const float* p = Whh + (size_t)(r2*512 + t)*HID + 8*j + 2*q;
    val = pack2d(p[0], p[1]);
  } else if (tid < OFF_WOUT) {                           // W_ih: rest = r*8+j
    int r = tid - OFF_WIH;
    int q = r & 3, t = (r >> 2) & 511, rest = r >> 11;
    int j = rest & 7, r2 = rest >> 3;
    const float* p = Wih + (size_t)(r2*512 + t)*IN + 8*j + 2*q;
    val = pack2d(p[0], p[1]);
  } else {                                               // W_out linear
    int r = tid - OFF_WOUT;
    const float* p = Wout + 2*r;
    val = pack2d(p[0], p[1]);
  }
  ws[tid] = val;
}

// ---------------- main: one block per batch element ----------------
// Thread t owns gate-rows t and t+512. ALL weights register-resident
// (W_hh 256 + W_ih 64 + W_out 16 = 336 regs/thread, V+A unified file;
// launch_bounds(512,1) -> 2 waves/SIMD -> ~512-reg budget, no spill <450).
// Zero per-step global/L2 weight traffic; h/x broadcast from LDS via
// v_dot2_f32_f16. Readout reads a bank-padded copy hs2 (stride 40 ushorts
// -> all 32 banks) to kill the 4-way conflict of the old seg*32 layout.
__global__ __launch_bounds__(512, 1) void lstm_main(
    const float* __restrict__ x, const float* __restrict__ h0, const float* __restrict__ c0,
    const float* __restrict__ bias, const float* __restrict__ b_out,
    const unsigned int* __restrict__ wsbase, float* __restrict__ out)
{
  const int b = blockIdx.x, t = threadIdx.x;

  __shared__ __align__(16) float lin_sh[G4];                  // 4 KiB
  __shared__ __align__(16) unsigned short hs[HID];            // h_t as f16 (linear, for broadcasts)
  __shared__ __align__(16) unsigned short hs2[8*40];          // h_t padded for readout (80B row stride)
  __shared__ __align__(16) unsigned short xs[IN];             // x_t as f16

  const unsigned int* WhhS = wsbase + OFF_WHH;
  const unsigned int* WihS = wsbase + OFF_WIH;
  const unsigned short* WoutS = (const unsigned short*)(wsbase + OFF_WOUT);

  // persistent register weights: full W_hh + full W_ih rows for gate-rows t, t+512
  uint4 whh0[NHH], whh1[NHH];
  #pragma unroll
  for (int j = 0; j < NHH; ++j) {
    whh0[j] = *(const uint4*)(WhhS + ((size_t)(0*NHH + j)*512 + t)*4);
    whh1[j] = *(const uint4*)(WhhS + ((size_t)(1*NHH + j)*512 + t)*4);
  }
  uint4 wih0[NIH], wih1[NIH];
  #pragma unroll
  for (int j = 0; j < NIH; ++j) {
    wih0[j] = *(const uint4*)(WihS + ((size_t)(0*NIH + j)*512 + t)*4);
    wih1[j] = *(const uint4*)(WihS + ((size_t)(1*NIH + j)*512 + t)*4);
  }
  // persistent readout weights: row o = t>>3, dims seg*32..seg*32+31 (seg = t&7)
  const int o = t >> 3, seg = t & 7;
  uint4 wo[4];
  #pragma unroll
  for (int q = 0; q < 4; ++q)
    wo[q] = *(const uint4*)(WoutS + (size_t)o*256 + seg*32 + 8*q);

  float c = 0.0f;
  if (t < HID) {
    c = c0[(size_t)b*HID + t];
    unsigned short hv0 = (unsigned short)(pack2d(h0[(size_t)b*HID + t], 0.0f) & 0xffffu);
    hs[t] = hv0;
    hs2[(t >> 5)*40 + (t & 31)] = hv0;
  } else if (t < HID + 32) {
    int i = t - HID;
    float2 xx = *(const float2*)(x + (size_t)b*IN + 2*i);   // x at s=0
    ((unsigned int*)xs)[i] = pack2d(xx.x, xx.y);
  }
  const float bz0 = bias[t], bz1 = bias[t + 512];
  const float bo  = b_out[o];
  __syncthreads();

  for (int s = 0; s < SEQ; ++s) {
    // prefetch next step's x (threads 256..287)
    float2 xn = make_float2(0.0f, 0.0f);
    if (t >= HID && t < HID + 32) {
      int sn = (s + 1 < SEQ) ? s + 1 : s;
      xn = *(const float2*)(x + ((size_t)sn*BATCH + b)*IN + 2*(t - HID));
    }

    // gate pre-activations; 2 accumulator chains per row so the fdot2
    // dependency (4cy latency, 2cy issue) stays throughput-bound.
    float l0a = bz0, l0b = 0.0f, l1a = bz1, l1b = 0.0f;
    #pragma unroll
    for (int j = 0; j < NHH; ++j) {
      uint4 hv = *(const uint4*)(hs + 8*j);
      if (j & 1) { mac8(whh0[j], hv, l0b); mac8(whh1[j], hv, l1b); }
      else       { mac8(whh0[j], hv, l0a); mac8(whh1[j], hv, l1a); }
    }
    #pragma unroll
    for (int j = 0; j < NIH; ++j) {
      uint4 xv = *(const uint4*)(xs + 8*j);
      if (j & 1) { mac8(wih0[j], xv, l0b); mac8(wih1[j], xv, l1b); }
      else       { mac8(wih0[j], xv, l0a); mac8(wih1[j], xv, l1a); }
    }
    lin_sh[t]       = l0a + l0b;
    lin_sh[t + 512] = l1a + l1b;

    __syncthreads();  // (a) lin complete

    if (t < HID) {
      float li  = lin_sh[t];
      float lf  = lin_sh[t + 256];
      float lg  = lin_sh[t + 512];
      float lo_ = lin_sh[t + 768];
      float ig = fsig(li), fg = fsig(lf), gg = ftanh_(lg), og = fsig(lo_);
      c = fg*c + ig*gg;
      float hn = og*ftanh_(c);
      unsigned short hp = (unsigned short)(pack2d(hn, 0.0f) & 0xffffu);
      hs[t] = hp;
      hs2[(t >> 5)*40 + (t & 31)] = hp;
    } else if (t < HID + 32) {
      ((unsigned int*)xs)[t - HID] = pack2d(xn.x, xn.y);
    }
    __syncthreads();  // (b) h_s / x_{s+1} published

    // fused readout: out[s,b,o] = W_out[o,:]·h_s + b_out[o]
    float acc = 0.0f;
    #pragma unroll
    for (int q = 0; q < 4; ++q) {
      uint4 hv = *(const uint4*)(hs2 + seg*40 + 8*q);
      mac8(wo[q], hv, acc);
    }
    acc += __shfl_xor(acc, 1);
    acc += __shfl_xor(acc, 2);
    acc += __shfl_xor(acc, 4);
    if (seg == 0) out[((size_t)s*BATCH + b)*OUTD + o] = acc + bo;
  }
}

extern "C" void kernel_launch(void* const* d_in, const int* in_sizes, int n_in,
                              void* d_out, int out_size, void* d_ws, size_t ws_size,
                              hipStream_t stream) {
  const float* x     = (const float*)d_in[0];
  const float* h0    = (const float*)d_in[1];
  const float* c0    = (const float*)d_in[2];
  const float* W_ih  = (const float*)d_in[3];
  const float* W_hh  = (const float*)d_in[4];
  const float* bias  = (const float*)d_in[5];
  const float* W_out = (const float*)d_in[6];
  const float* b_out = (const float*)d_in[7];
  float* out = (float*)d_out;
  unsigned int* ws = (unsigned int*)d_ws;

  hipLaunchKernelGGL(prep_weights, dim3((TOTAL_DW + 255)/256), dim3(256), 0, stream,
                     W_hh, W_ih, W_out, ws);
  hipLaunchKernelGGL(lstm_main, dim3(BATCH), dim3(T), 0, stream,
                     x, h0, c0, bias, b_out, ws, out);
}

// Round 2
// 5337.910 us; speedup vs baseline: 3.2335x; 3.2335x over previous
//
#include <hip/hip_runtime.h>
#include <cstdint>

#define SEQ   2048
#define BATCH 128
#define IN    64
#define HID   256
#define OUTD  64

#define T     512
#define NHH   32   // W_hh 8-dim chunks per row (256 dims)
#define NIH   8    // W_ih 8-dim chunks per row (64 dims)

// ---- ws layout in dwords ----
#define OFF_WHH  0
#define SZ_WHH   (2*NHH*512*4)           // 131072 dw (= full W_hh f16, both halves)
#define OFF_WIH  (OFF_WHH+SZ_WHH)        // 131072
#define SZ_WIH   (2*NIH*512*4)           // 32768
#define OFF_WOUT (OFF_WIH+SZ_WIH)        // 163840
#define SZ_WOUT  8192                    // 64*256 f16
#define OFF_EXCH (OFF_WOUT+SZ_WOUT)      // 172032
#define SZ_EXCH  (BATCH*2*2*512)         // 262144 dw: [block(256)][parity(2)][512] floats
#define OFF_FLAG (OFF_EXCH+SZ_EXCH)      // 434176
#define SZ_FLAG  (BATCH*2*16)            // 4096 dw: one flag per block, 64B stride
#define TOTAL_DW (OFF_FLAG+SZ_FLAG)      // 438272 dw = 1.75 MB

typedef _Float16 f16x2 __attribute__((ext_vector_type(2)));

__device__ __forceinline__ float fexp2(float v) { return __builtin_amdgcn_exp2f(v); }
__device__ __forceinline__ float frcp(float v)  { return __builtin_amdgcn_rcpf(v); }
__device__ __forceinline__ float fsig(float v)  { return frcp(1.0f + fexp2(v * -1.44269504088896f)); }
__device__ __forceinline__ float ftanh_(float v){ return 1.0f - 2.0f * frcp(1.0f + fexp2(v * 2.88539008177793f)); }

__device__ __forceinline__ unsigned int pack2d(float a, float b) {
  unsigned short lo = __builtin_bit_cast(unsigned short, (_Float16)a);
  unsigned short hi = __builtin_bit_cast(unsigned short, (_Float16)b);
  return (unsigned int)lo | ((unsigned int)hi << 16);
}

__device__ __forceinline__ float dot2f(unsigned int w, unsigned int h, float acc) {
#if __has_builtin(__builtin_amdgcn_fdot2)
  return __builtin_amdgcn_fdot2(__builtin_bit_cast(f16x2, w), __builtin_bit_cast(f16x2, h), acc, false);
#else
  f16x2 a = __builtin_bit_cast(f16x2, w), b = __builtin_bit_cast(f16x2, h);
  return acc + (float)a.x * (float)b.x + (float)a.y * (float)b.y;
#endif
}

__device__ __forceinline__ void mac8(uint4 w, uint4 h, float& acc) {
  acc = dot2f(w.x, h.x, acc);
  acc = dot2f(w.y, h.y, acc);
  acc = dot2f(w.z, h.z, acc);
  acc = dot2f(w.w, h.w, acc);
}

// ---------------- prep: fp32 weights -> packed f16 layouts; zero sync flags ----------------
__global__ void prep_weights(const float* __restrict__ Whh, const float* __restrict__ Wih,
                             const float* __restrict__ Wout, unsigned int* __restrict__ ws) {
  int tid = blockIdx.x * 256 + threadIdx.x;
  if (tid >= TOTAL_DW) return;
  if (tid >= OFF_FLAG) { ws[tid] = 0u; return; }   // reset flags every launch (graph-replay safe)
  if (tid >= OFF_EXCH) return;                     // exchange buffers need no init
  unsigned int val;
  if (tid < OFF_WIH) {                             // W_hh: [half][j][t][q]
    int q = tid & 3, t = (tid >> 2) & 511, rest = tid >> 11;
    int j = rest & 31, half = rest >> 5;
    const float* p = Whh + (size_t)(half*512 + t)*HID + 8*j + 2*q;
    val = pack2d(p[0], p[1]);
  } else if (tid < OFF_WOUT) {                     // W_ih: [half][j][t][q]
    int r = tid - OFF_WIH;
    int q = r & 3, t = (r >> 2) & 511, rest = r >> 11;
    int j = rest & 7, half = rest >> 3;
    const float* p = Wih + (size_t)(half*512 + t)*IN + 8*j + 2*q;
    val = pack2d(p[0], p[1]);
  } else {                                         // W_out linear f16
    int r = tid - OFF_WOUT;
    const float* p = Wout + 2*r;
    val = pack2d(p[0], p[1]);
  }
  ws[tid] = val;
}

// ---------------- main: TWO blocks per batch element (grid = 256 = one block/CU) ----------------
// Block 2b+0 owns gate rows 0..511 (i,f); block 2b+1 owns rows 512..1023 (g,o).
// Each thread owns ONE gate row: 128 dw W_hh + 32 dw W_ih + 8 dw W_out = 168 persistent
// regs, under the 256-reg cap of an 8-wave block (512-reg/SIMD pool) -> true residency.
// Per step the pair exchanges its 512 lins through L3 (agent-scope atomics, parity
// double-buffer, monotonic flag); both blocks redundantly compute identical h,c.
// 84 KiB static LDS forces 1 block/CU -> all 256 blocks co-resident -> spin is deadlock-free.
__global__ __launch_bounds__(512, 2) void lstm_main(
    const float* __restrict__ x, const float* __restrict__ h0, const float* __restrict__ c0,
    const float* __restrict__ bias, const float* __restrict__ b_out,
    unsigned int* __restrict__ ws, float* __restrict__ out)
{
  const int bid = blockIdx.x;
  const int b = bid >> 1, half = bid & 1, t = threadIdx.x;

  __shared__ __align__(16) unsigned char smem[86016];   // 84 KiB: occupancy clamp (see above)
  float*          lin_sh = (float*)smem;                // 512 floats   @ 0
  unsigned short* hs     = (unsigned short*)(smem + 2048); // 256 ushorts: h_t, linear (broadcast reads)
  unsigned short* hs2    = (unsigned short*)(smem + 2560); // 16 rows x 24 ushorts: padded for readout
  unsigned short* xs     = (unsigned short*)(smem + 3328); // 64 ushorts: x_t

  const unsigned int* WhhS = ws + OFF_WHH;
  const unsigned int* WihS = ws + OFF_WIH;
  const unsigned short* WoutS = (const unsigned short*)(ws + OFF_WOUT);
  float* exch = (float*)(ws + OFF_EXCH);
  float* ebuf_my   = exch + (size_t)bid      * 1024;    // [parity][512]
  float* ebuf_peer = exch + (size_t)(bid ^ 1)* 1024;
  unsigned int* flagv = ws + OFF_FLAG;
  unsigned int* myflag = flagv + (size_t)bid * 16;
  unsigned int* pflag  = flagv + (size_t)(bid ^ 1) * 16;

  // persistent register weights: one gate row per thread
  uint4 whh[NHH];
  #pragma unroll
  for (int j = 0; j < NHH; ++j)
    whh[j] = *(const uint4*)(WhhS + ((size_t)(half*NHH + j)*512 + t)*4);
  uint4 wih[NIH];
  #pragma unroll
  for (int j = 0; j < NIH; ++j)
    wih[j] = *(const uint4*)(WihS + ((size_t)(half*NIH + j)*512 + t)*4);
  // readout: this block handles 32 outputs; 16 threads x 16 dims each
  const int oglob = half*32 + (t >> 4), seg = t & 15;
  uint4 wo[2];
  #pragma unroll
  for (int q = 0; q < 2; ++q)
    wo[q] = *(const uint4*)(WoutS + (size_t)oglob*256 + seg*16 + q*8);

  float c = 0.0f;
  if (t < HID) {
    c = c0[(size_t)b*HID + t];
    unsigned short hv0 = (unsigned short)(pack2d(h0[(size_t)b*HID + t], 0.0f) & 0xffffu);
    hs[t] = hv0;
    hs2[(t >> 4)*24 + (t & 15)] = hv0;
  } else if (t < HID + 32) {
    int i = t - HID;
    float2 xx = *(const float2*)(x + (size_t)b*IN + 2*i);   // x at s=0
    ((unsigned int*)xs)[i] = pack2d(xx.x, xx.y);
  }
  const float bz = bias[half*512 + t];
  const float bo = b_out[oglob];
  __syncthreads();

  for (int s = 0; s < SEQ; ++s) {
    // prefetch next step's x (threads 256..287)
    float2 xn = make_float2(0.0f, 0.0f);
    if (t >= HID && t < HID + 32) {
      int sn = (s + 1 < SEQ) ? s + 1 : s;
      xn = *(const float2*)(x + ((size_t)sn*BATCH + b)*IN + 2*(t - HID));
    }

    // one gate row: 160 fdot2 in 2 chains (4cy dep vs 2cy issue)
    float la = bz, lb = 0.0f;
    #pragma unroll
    for (int j = 0; j < NHH; j += 2) {
      uint4 h0v = *(const uint4*)(hs + 8*j);
      uint4 h1v = *(const uint4*)(hs + 8*j + 8);
      mac8(whh[j],   h0v, la);
      mac8(whh[j+1], h1v, lb);
    }
    #pragma unroll
    for (int j = 0; j < NIH; j += 2) {
      uint4 x0v = *(const uint4*)(xs + 8*j);
      uint4 x1v = *(const uint4*)(xs + 8*j + 8);
      mac8(wih[j],   x0v, la);
      mac8(wih[j+1], x1v, lb);
    }
    float lin = la + lb;
    lin_sh[t] = lin;
    // publish to peer (agent scope = cross-XCD coherent at L3)
    __hip_atomic_store(ebuf_my + (s & 1)*512 + t, lin,
                       __ATOMIC_RELAXED, __HIP_MEMORY_SCOPE_AGENT);

    __syncthreads();  // (a) lin_sh complete; also drains exch stores (vmcnt(0) before s_barrier)

    if (t == 0)       // all block's stores are complete at L3 -> flag can be relaxed
      __hip_atomic_store(myflag, (unsigned)(s + 1),
                         __ATOMIC_RELAXED, __HIP_MEMORY_SCOPE_AGENT);

    if (t < HID) {
      float own_a = lin_sh[t];          // half0: i-row t   ; half1: g-row t
      float own_b = lin_sh[t + 256];    // half0: f-row t   ; half1: o-row t
      while (__hip_atomic_load(pflag, __ATOMIC_RELAXED, __HIP_MEMORY_SCOPE_AGENT) <= (unsigned)s) {}
      __asm__ volatile("" ::: "memory");
      float* pb = ebuf_peer + (s & 1)*512;
      float p_a = __hip_atomic_load(pb + t,       __ATOMIC_RELAXED, __HIP_MEMORY_SCOPE_AGENT);
      float p_b = __hip_atomic_load(pb + t + 256, __ATOMIC_RELAXED, __HIP_MEMORY_SCOPE_AGENT);
      float li, lf, lg, lo_;
      if (half == 0) { li = own_a; lf = own_b; lg = p_a;  lo_ = p_b; }
      else           { lg = own_a; lo_ = own_b; li = p_a; lf  = p_b; }
      float ig = fsig(li), fg = fsig(lf), gg = ftanh_(lg), og = fsig(lo_);
      c = fg*c + ig*gg;
      float hn = og*ftanh_(c);
      unsigned short hp = (unsigned short)(pack2d(hn, 0.0f) & 0xffffu);
      hs[t] = hp;
      hs2[(t >> 4)*24 + (t & 15)] = hp;
    } else if (t < HID + 32) {
      ((unsigned int*)xs)[t - HID] = pack2d(xn.x, xn.y);
    }
    __syncthreads();  // (b) h_s / x_{s+1} published

    // fused readout: this block's 32 outputs; 16 lanes x 16 dims each
    float acc = 0.0f;
    #pragma unroll
    for (int q = 0; q < 2; ++q) {
      uint4 hv = *(const uint4*)(hs2 + seg*24 + 8*q);
      mac8(wo[q], hv, acc);
    }
    acc += __shfl_xor(acc, 1);
    acc += __shfl_xor(acc, 2);
    acc += __shfl_xor(acc, 4);
    acc += __shfl_xor(acc, 8);
    if (seg == 0) out[((size_t)s*BATCH + b)*OUTD + oglob] = acc + bo;
  }
}

extern "C" void kernel_launch(void* const* d_in, const int* in_sizes, int n_in,
                              void* d_out, int out_size, void* d_ws, size_t ws_size,
                              hipStream_t stream) {
  const float* x     = (const float*)d_in[0];
  const float* h0    = (const float*)d_in[1];
  const float* c0    = (const float*)d_in[2];
  const float* W_ih  = (const float*)d_in[3];
  const float* W_hh  = (const float*)d_in[4];
  const float* bias  = (const float*)d_in[5];
  const float* W_out = (const float*)d_in[6];
  const float* b_out = (const float*)d_in[7];
  float* out = (float*)d_out;
  unsigned int* ws = (unsigned int*)d_ws;

  hipLaunchKernelGGL(prep_weights, dim3((TOTAL_DW + 255)/256), dim3(256), 0, stream,
                     W_hh, W_ih, W_out, ws);
  hipLaunchKernelGGL(lstm_main, dim3(2*BATCH), dim3(T), 0, stream,
                     x, h0, c0, bias, b_out, ws, out);
}